// Round 6
// baseline (813.145 us; speedup 1.0000x reference)
//
#include <hip/hip_runtime.h>

typedef unsigned short u16;
typedef unsigned int u32;
typedef __attribute__((ext_vector_type(8))) short bf16x8;
typedef __attribute__((ext_vector_type(4))) float f32x4;

#define LDK 72   // A-tile LDS stride (64 + 8 pad)

__device__ __forceinline__ u16 f2bf(float f) {
    u32 u = __float_as_uint(f);
    u += 0x7fffu + ((u >> 16) & 1u);   // round-to-nearest-even
    return (u16)(u >> 16);
}

__device__ __forceinline__ f32x4 mfma16(bf16x8 a, bf16x8 b, f32x4 c) {
    return __builtin_amdgcn_mfma_f32_16x16x32_bf16(a, b, c, 0, 0, 0);
}

// ---------------- prep: fold numeric features ----------------

__global__ __launch_bounds__(256) void prep_u_kernel(
    const float* __restrict__ w_num, const float* __restrict__ b_num,
    const float* __restrict__ W_first, float* __restrict__ U, float* __restrict__ P)
{
    __shared__ float wrow[256];
    __shared__ float brow[256];
    int j = threadIdx.x, f = blockIdx.x;
    wrow[j] = w_num[f * 256 + j];
    brow[j] = b_num[f * 256 + j];
    __syncthreads();
    float au = 0.f, ap = 0.f;
    for (int k = 0; k < 256; k++) {
        float w = W_first[(size_t)((f << 8) + k) * 256 + j];
        au = fmaf(wrow[k], w, au);
        ap = fmaf(brow[k], w, ap);
    }
    U[f * 256 + j] = au;
    P[f * 256 + j] = ap;
}

__global__ __launch_bounds__(256) void prep_c0_kernel(
    const float* __restrict__ b_first, const float* __restrict__ P, float* __restrict__ c0)
{
    int j = threadIdx.x;
    float a = b_first[j];
    for (int f = 0; f < 32; f++) a += P[f * 256 + j];
    c0[j] = a;
}

// ---------------- prep: LDS-tiled transpose f32 -> bf16 ----------------
__global__ __launch_bounds__(256) void transpose_kernel(
    const float* __restrict__ in, u16* __restrict__ out,
    int R, int C, int ldo, int k_off, size_t in_stride, size_t out_stride)
{
    __shared__ float t[64][65];
    in  += (size_t)blockIdx.z * in_stride;
    out += (size_t)blockIdx.z * out_stride;
    const int tid = threadIdx.x;
    const int r0 = blockIdx.x * 64, c0 = blockIdx.y * 64;
#pragma unroll
    for (int i = 0; i < 16; i++) {
        int e = tid + i * 256;
        int r = e >> 6, c = e & 63;
        float v = (r0 + r < R) ? in[(size_t)(r0 + r) * C + c0 + c] : 0.f;
        t[c][r] = v;
    }
    __syncthreads();
#pragma unroll
    for (int i = 0; i < 2; i++) {
        int e = tid + i * 256;
        int c = e >> 3, r8 = (e & 7) * 8;
        u16 tmp[8];
#pragma unroll
        for (int x = 0; x < 8; x++) tmp[x] = f2bf(t[c][r8 + x]);
        *(bf16x8*)&out[(size_t)(c0 + c) * ldo + k_off + r0 + r8] = *(bf16x8*)tmp;
    }
}

// ---------------- first layer: gathered-A GEMM, ping-pong buffers ----------------
#define FBM 32

#define GATHER(KQ, G0, G1)                                                    \
    {                                                                         \
        int chunk = tid;                                                      \
        int r = chunk >> 4, c4 = chunk & 15;                                  \
        int k = (KQ) + c4 * 4;                                                \
        if (k < 4096) {                                                       \
            int rowi = sidx[r * 16 + (k >> 8)];                               \
            G0 = *(const float4*)&cemb[(size_t)rowi * 256 + (k & 255)];       \
        } else if (k < 4128) {                                                \
            int c = k - 4096;                                                 \
            G0.x = sx[r * 32 + c];     G0.y = sx[r * 32 + c + 1];             \
            G0.z = sx[r * 32 + c + 2]; G0.w = sx[r * 32 + c + 3];             \
        } else G0 = make_float4(0.f, 0.f, 0.f, 0.f);                          \
        chunk = tid + 256;                                                    \
        r = chunk >> 4; c4 = chunk & 15;                                      \
        k = (KQ) + c4 * 4;                                                    \
        if (k < 4096) {                                                       \
            int rowi = sidx[r * 16 + (k >> 8)];                               \
            G1 = *(const float4*)&cemb[(size_t)rowi * 256 + (k & 255)];       \
        } else if (k < 4128) {                                                \
            int c = k - 4096;                                                 \
            G1.x = sx[r * 32 + c];     G1.y = sx[r * 32 + c + 1];             \
            G1.z = sx[r * 32 + c + 2]; G1.w = sx[r * 32 + c + 3];             \
        } else G1 = make_float4(0.f, 0.f, 0.f, 0.f);                          \
    }

__global__ __launch_bounds__(256) void first_gemm_kernel(
    const u16* __restrict__ BT, const float* __restrict__ bias,
    float* __restrict__ outF,
    const int* __restrict__ cidx, const float* __restrict__ cemb,
    const float* __restrict__ xnum)
{
    __shared__ __align__(16) u16 Ab[2][FBM * LDK];    //  9216 B, padded
    __shared__ __align__(16) u16 Bb[2][256 * 64];     // 65536 B, swizzled no-pad
    __shared__ int   sidx[FBM * 16];
    __shared__ float sx[FBM * 32];

    const int tid = threadIdx.x;
    const int lane = tid & 63;
    const int wv = tid >> 6;
    const int quad = lane >> 4;
    const int l16 = lane & 15;
    const int m0 = blockIdx.x * FBM;

#pragma unroll
    for (int i = 0; i < 2; i++) sidx[tid + i * 256] = cidx[m0 * 16 + tid + i * 256];
    {
        float4 v = *(const float4*)&xnum[(size_t)m0 * 32 + tid * 4];
        sx[tid * 4 + 0] = v.x; sx[tid * 4 + 1] = v.y;
        sx[tid * 4 + 2] = v.z; sx[tid * 4 + 3] = v.w;
    }
    __syncthreads();

    f32x4 acc[2][4];
#pragma unroll
    for (int i = 0; i < 2; i++)
#pragma unroll
        for (int j = 0; j < 4; j++) acc[i][j] = (f32x4){0.f, 0.f, 0.f, 0.f};

#define WRITE_A(BUF, G0, G1)                                                  \
    {                                                                         \
        int r = tid >> 4, c4 = tid & 15;                                      \
        u16* dst = &Ab[BUF][r * LDK + c4 * 4];                                \
        dst[0] = f2bf(G0.x); dst[1] = f2bf(G0.y);                             \
        dst[2] = f2bf(G0.z); dst[3] = f2bf(G0.w);                             \
        int chunk = tid + 256;                                                \
        r = chunk >> 4; c4 = chunk & 15;                                      \
        dst = &Ab[BUF][r * LDK + c4 * 4];                                     \
        dst[0] = f2bf(G1.x); dst[1] = f2bf(G1.y);                             \
        dst[2] = f2bf(G1.z); dst[3] = f2bf(G1.w);                             \
    }

#define DMA_B(BUF, KQ)                                                        \
    _Pragma("unroll")                                                         \
    for (int it = 0; it < 8; it++) {                                          \
        int chunk = it * 256 + tid;                                           \
        int r = chunk >> 3;                                                   \
        int c8 = (chunk & 7) ^ (r & 7);                                       \
        const u16* src = &BT[(size_t)r * 4160 + (KQ) + c8 * 8];               \
        __builtin_amdgcn_global_load_lds(                                     \
            (const __attribute__((address_space(1))) void*)src,               \
            (__attribute__((address_space(3))) void*)&Bb[BUF][(it * 256 + wv * 64) * 8], \
            16, 0, 0);                                                        \
    }

    // prologue: stage tile 0, prefetch gather for tile 1
    float4 ga0, ga1;
    GATHER(0, ga0, ga1);
    WRITE_A(0, ga0, ga1);
    DMA_B(0, 0);
    GATHER(64, ga0, ga1);
    __syncthreads();   // tile 0 staged

    for (int k0 = 0; k0 < 4160; k0 += 64) {
        const int cur = (k0 >> 6) & 1, nxt = cur ^ 1;
        // stage tile n+1 (overlaps MFMA of tile n), prefetch gather n+2
        if (k0 + 64 < 4160) {
            WRITE_A(nxt, ga0, ga1);
            DMA_B(nxt, k0 + 64);
            if (k0 + 128 < 4160) GATHER(k0 + 128, ga0, ga1);
        }
#pragma unroll
        for (int kk = 0; kk < 64; kk += 32) {
            bf16x8 af[2], bfr[4];
#pragma unroll
            for (int i = 0; i < 2; i++)
                af[i] = *(const bf16x8*)&Ab[cur][(i * 16 + l16) * LDK + kk + quad * 8];
#pragma unroll
            for (int j = 0; j < 4; j++) {
                int row = wv * 64 + j * 16 + l16;
                int c8L = quad + (kk >> 3);
                bfr[j] = *(const bf16x8*)&Bb[cur][row * 64 + ((c8L ^ (row & 7)) * 8)];
            }
#pragma unroll
            for (int i = 0; i < 2; i++)
#pragma unroll
                for (int j = 0; j < 4; j++)
                    acc[i][j] = mfma16(af[i], bfr[j], acc[i][j]);
        }
        __syncthreads();   // nxt staged AND cur reads done
    }

    // C/D layout: col = lane&15, row = (lane>>4)*4 + reg
#pragma unroll
    for (int i = 0; i < 2; i++) {
#pragma unroll
        for (int j = 0; j < 4; j++) {
            int col = wv * 64 + j * 16 + l16;
            float bs = bias[col];
#pragma unroll
            for (int r = 0; r < 4; r++) {
                int row = m0 + i * 16 + quad * 4 + r;
                outF[(size_t)row * 256 + col] = acc[i][j][r] + bs;
            }
        }
    }
}

// ---------------- fused residual layer: BM=16, high occupancy ----------------
// grid 1024 -> 4 blocks/CU, 16 waves/CU (VGPR capped to 128 by launch_bounds).
// LN (wave-per-row, coalesced float4) -> hn(LDS) -> FC1+ReLU -> hid(LDS) -> FC2 + resid.
__global__ __launch_bounds__(256, 4) void layer_kernel(
    float* __restrict__ h,
    const float* __restrict__ g, const float* __restrict__ bta,
    const u16* __restrict__ W1, const float* __restrict__ b1,
    const u16* __restrict__ W2, const float* __restrict__ b2)
{
    __shared__ __align__(16) u16 hn[16 * 264];    //  8448 B
    __shared__ __align__(16) u16 hid[16 * 520];   // 16640 B
    const int tid  = threadIdx.x;
    const int lane = tid & 63;
    const int wv   = tid >> 6;
    const int quad = lane >> 4;
    const int l16  = lane & 15;
    const int m0   = blockIdx.x * 16;

    // ---- phase A: LN (wave per row, 4 rounds, coalesced) ----
    float4 gv4 = *(const float4*)&g[lane * 4];
    float4 bv4 = *(const float4*)&bta[lane * 4];
#pragma unroll
    for (int rr = 0; rr < 4; rr++) {
        int row = rr * 4 + wv;
        float4 x = *(const float4*)&h[(size_t)(m0 + row) * 256 + lane * 4];
        float s  = x.x + x.y + x.z + x.w;
        float s2 = x.x * x.x + x.y * x.y + x.z * x.z + x.w * x.w;
#pragma unroll
        for (int o = 32; o > 0; o >>= 1) { s += __shfl_xor(s, o); s2 += __shfl_xor(s2, o); }
        float mu = s * (1.f / 256.f);
        float rs = rsqrtf(s2 * (1.f / 256.f) - mu * mu + 1e-5f);
        ushort4 o4;
        o4.x = f2bf((x.x - mu) * rs * gv4.x + bv4.x);
        o4.y = f2bf((x.y - mu) * rs * gv4.y + bv4.y);
        o4.z = f2bf((x.z - mu) * rs * gv4.z + bv4.z);
        o4.w = f2bf((x.w - mu) * rs * gv4.w + bv4.w);
        *(ushort4*)&hn[row * 264 + lane * 4] = o4;
    }
    __syncthreads();

    // ---- phase B: FC1 (wave owns 128 of 512 cols) ----
    float b1v[8];
#pragma unroll
    for (int j = 0; j < 8; j++) b1v[j] = b1[wv * 128 + j * 16 + l16];
    f32x4 acc1[8];
#pragma unroll
    for (int j = 0; j < 8; j++) acc1[j] = (f32x4){0.f, 0.f, 0.f, 0.f};
#pragma unroll 2
    for (int kk = 0; kk < 256; kk += 32) {
        bf16x8 af = *(const bf16x8*)&hn[l16 * 264 + kk + quad * 8];
        bf16x8 bw[8];
#pragma unroll
        for (int j = 0; j < 8; j++)
            bw[j] = *(const bf16x8*)&W1[(size_t)(wv * 128 + j * 16 + l16) * 256 + kk + quad * 8];
#pragma unroll
        for (int j = 0; j < 8; j++) acc1[j] = mfma16(af, bw[j], acc1[j]);
    }
#pragma unroll
    for (int j = 0; j < 8; j++)
#pragma unroll
        for (int r = 0; r < 4; r++) {
            float v = acc1[j][r] + b1v[j];
            v = v > 0.f ? v : 0.f;
            hid[(quad * 4 + r) * 520 + wv * 128 + j * 16 + l16] = f2bf(v);
        }
    __syncthreads();

    // ---- phase C: FC2 (wave owns 64 of 256 cols) + bias + residual ----
    float b2v[4];
#pragma unroll
    for (int j = 0; j < 4; j++) b2v[j] = b2[wv * 64 + j * 16 + l16];
    f32x4 acc2[4];
#pragma unroll
    for (int j = 0; j < 4; j++) acc2[j] = (f32x4){0.f, 0.f, 0.f, 0.f};
#pragma unroll 2
    for (int kk = 0; kk < 512; kk += 32) {
        bf16x8 af = *(const bf16x8*)&hid[l16 * 520 + kk + quad * 8];
        bf16x8 bw[4];
#pragma unroll
        for (int j = 0; j < 4; j++)
            bw[j] = *(const bf16x8*)&W2[(size_t)(wv * 64 + j * 16 + l16) * 512 + kk + quad * 8];
#pragma unroll
        for (int j = 0; j < 4; j++) acc2[j] = mfma16(af, bw[j], acc2[j]);
    }
#pragma unroll
    for (int j = 0; j < 4; j++) {
        int col = wv * 64 + j * 16 + l16;
#pragma unroll
        for (int r = 0; r < 4; r++) {
            int row = m0 + quad * 4 + r;
            float v = acc2[j][r] + b2v[j];
            h[(size_t)row * 256 + col] = v + h[(size_t)row * 256 + col];
        }
    }
}

// ---------------- head: final LN + [256 x 2] matvec ----------------
__global__ __launch_bounds__(256) void head_kernel(
    const float* __restrict__ h, const float* __restrict__ g,
    const float* __restrict__ bta, const float* __restrict__ Wh,
    const float* __restrict__ bh, float* __restrict__ out)
{
    int lane = threadIdx.x & 63;
    int row = blockIdx.x * 4 + (threadIdx.x >> 6);
    const float4 x = *(const float4*)&h[(size_t)row * 256 + lane * 4];
    float s = x.x + x.y + x.z + x.w;
    float s2 = x.x * x.x + x.y * x.y + x.z * x.z + x.w * x.w;
    for (int o = 32; o > 0; o >>= 1) { s += __shfl_xor(s, o); s2 += __shfl_xor(s2, o); }
    float mu = s * (1.f / 256.f);
    float rs = rsqrtf(s2 * (1.f / 256.f) - mu * mu + 1e-5f);
    float4 gv = *(const float4*)&g[lane * 4];
    float4 bv = *(const float4*)&bta[lane * 4];
    float xn0 = (x.x - mu) * rs * gv.x + bv.x;
    float xn1 = (x.y - mu) * rs * gv.y + bv.y;
    float xn2 = (x.z - mu) * rs * gv.z + bv.z;
    float xn3 = (x.w - mu) * rs * gv.w + bv.w;
    float4 wa = *(const float4*)&Wh[lane * 8];
    float4 wb = *(const float4*)&Wh[lane * 8 + 4];
    float d0 = xn0 * wa.x + xn1 * wa.z + xn2 * wb.x + xn3 * wb.z;
    float d1 = xn0 * wa.y + xn1 * wa.w + xn2 * wb.y + xn3 * wb.w;
    for (int o = 32; o > 0; o >>= 1) { d0 += __shfl_xor(d0, o); d1 += __shfl_xor(d1, o); }
    if (lane == 0) {
        out[(size_t)row * 2 + 0] = d0 + bh[0];
        out[(size_t)row * 2 + 1] = d1 + bh[1];
    }
}

// ---------------- launch ----------------
extern "C" void kernel_launch(void* const* d_in, const int* in_sizes, int n_in,
                              void* d_out, int out_size, void* d_ws, size_t ws_size,
                              hipStream_t stream)
{
    const float* x_num   = (const float*)d_in[0];
    const int*   cidx    = (const int*)d_in[1];
    const float* w_num   = (const float*)d_in[2];
    const float* b_num   = (const float*)d_in[3];
    const float* cemb    = (const float*)d_in[4];
    const float* W_first = (const float*)d_in[5];
    const float* b_first = (const float*)d_in[6];
    const float* ln_g    = (const float*)d_in[7];
    const float* ln_b    = (const float*)d_in[8];
    const float* W1s     = (const float*)d_in[9];
    const float* b1s     = (const float*)d_in[10];
    const float* W2s     = (const float*)d_in[11];
    const float* b2s     = (const float*)d_in[12];
    const float* g_f     = (const float*)d_in[13];
    const float* beta_f  = (const float*)d_in[14];
    const float* W_head  = (const float*)d_in[15];
    const float* b_head  = (const float*)d_in[16];
    float* out = (float*)d_out;

    char* ws = (char*)d_ws;
    float* U   = (float*)(ws + 0);          //  32 KB
    float* c0  = (float*)(ws + 32768);      //   1 KB
    float* P   = (float*)(ws + 33792);      //  32 KB
    u16* WcT   = (u16*)(ws + 66560);        // 256 x 4160 bf16
    u16* W1T   = (u16*)(ws + 2196480);      // 8 x 512 x 256 bf16
    u16* W2T   = (u16*)(ws + 4293632);      // 8 x 256 x 512 bf16
    float* h   = (float*)(ws + 6390784);    // 16384 x 256 f32

    prep_u_kernel<<<32, 256, 0, stream>>>(w_num, b_num, W_first, U, P);
    prep_c0_kernel<<<1, 256, 0, stream>>>(b_first, P, c0);
    transpose_kernel<<<dim3(64, 4, 1), 256, 0, stream>>>(
        W_first + (size_t)8192 * 256, WcT, 4096, 256, 4160, 0, 0, 0);
    transpose_kernel<<<dim3(1, 4, 1), 256, 0, stream>>>(
        U, WcT, 32, 256, 4160, 4096, 0, 0);
    transpose_kernel<<<dim3(4, 8, 8), 256, 0, stream>>>(
        W1s, W1T, 256, 512, 256, 0, 131072, 131072);
    transpose_kernel<<<dim3(8, 4, 8), 256, 0, stream>>>(
        W2s, W2T, 512, 256, 512, 0, 131072, 131072);

    first_gemm_kernel<<<512, 256, 0, stream>>>(
        WcT, c0, h, cidx, cemb, x_num);

    for (int l = 0; l < 8; l++) {
        layer_kernel<<<1024, 256, 0, stream>>>(
            h, ln_g + l * 256, ln_b + l * 256,
            W1T + (size_t)l * 131072, b1s + l * 512,
            W2T + (size_t)l * 131072, b2s + l * 256);
    }
    head_kernel<<<4096, 256, 0, stream>>>(h, g_f, beta_f, W_head, b_head, out);
}

// Round 7
// 719.022 us; speedup vs baseline: 1.1309x; 1.1309x over previous
//
#include <hip/hip_runtime.h>

typedef unsigned short u16;
typedef unsigned int u32;
typedef __attribute__((ext_vector_type(8))) short bf16x8;
typedef __attribute__((ext_vector_type(4))) float f32x4;

#define LDK 72   // A-tile LDS stride (64 + 8 pad)

__device__ __forceinline__ u16 f2bf(float f) {
    u32 u = __float_as_uint(f);
    u += 0x7fffu + ((u >> 16) & 1u);   // round-to-nearest-even
    return (u16)(u >> 16);
}

__device__ __forceinline__ f32x4 mfma16(bf16x8 a, bf16x8 b, f32x4 c) {
    return __builtin_amdgcn_mfma_f32_16x16x32_bf16(a, b, c, 0, 0, 0);
}

// ---------------- prep: fold numeric features ----------------

__global__ __launch_bounds__(256) void prep_u_kernel(
    const float* __restrict__ w_num, const float* __restrict__ b_num,
    const float* __restrict__ W_first, float* __restrict__ U, float* __restrict__ P)
{
    __shared__ float wrow[256];
    __shared__ float brow[256];
    int j = threadIdx.x, f = blockIdx.x;
    wrow[j] = w_num[f * 256 + j];
    brow[j] = b_num[f * 256 + j];
    __syncthreads();
    float au = 0.f, ap = 0.f;
    for (int k = 0; k < 256; k++) {
        float w = W_first[(size_t)((f << 8) + k) * 256 + j];
        au = fmaf(wrow[k], w, au);
        ap = fmaf(brow[k], w, ap);
    }
    U[f * 256 + j] = au;
    P[f * 256 + j] = ap;
}

__global__ __launch_bounds__(256) void prep_c0_kernel(
    const float* __restrict__ b_first, const float* __restrict__ P, float* __restrict__ c0)
{
    int j = threadIdx.x;
    float a = b_first[j];
    for (int f = 0; f < 32; f++) a += P[f * 256 + j];
    c0[j] = a;
}

// ---------------- prep: LDS-tiled transpose f32 -> bf16 ----------------
__global__ __launch_bounds__(256) void transpose_kernel(
    const float* __restrict__ in, u16* __restrict__ out,
    int R, int C, int ldo, int k_off, size_t in_stride, size_t out_stride)
{
    __shared__ float t[64][65];
    in  += (size_t)blockIdx.z * in_stride;
    out += (size_t)blockIdx.z * out_stride;
    const int tid = threadIdx.x;
    const int r0 = blockIdx.x * 64, c0 = blockIdx.y * 64;
#pragma unroll
    for (int i = 0; i < 16; i++) {
        int e = tid + i * 256;
        int r = e >> 6, c = e & 63;
        float v = (r0 + r < R) ? in[(size_t)(r0 + r) * C + c0 + c] : 0.f;
        t[c][r] = v;
    }
    __syncthreads();
#pragma unroll
    for (int i = 0; i < 2; i++) {
        int e = tid + i * 256;
        int c = e >> 3, r8 = (e & 7) * 8;
        u16 tmp[8];
#pragma unroll
        for (int x = 0; x < 8; x++) tmp[x] = f2bf(t[c][r8 + x]);
        *(bf16x8*)&out[(size_t)(c0 + c) * ldo + k_off + r0 + r8] = *(bf16x8*)tmp;
    }
}

// ---------------- first layer: gathered-A GEMM, ping-pong buffers ----------------
#define FBM 32

#define GATHER(KQ, G0, G1)                                                    \
    {                                                                         \
        int chunk = tid;                                                      \
        int r = chunk >> 4, c4 = chunk & 15;                                  \
        int k = (KQ) + c4 * 4;                                                \
        if (k < 4096) {                                                       \
            int rowi = sidx[r * 16 + (k >> 8)];                               \
            G0 = *(const float4*)&cemb[(size_t)rowi * 256 + (k & 255)];       \
        } else if (k < 4128) {                                                \
            int c = k - 4096;                                                 \
            G0.x = sx[r * 32 + c];     G0.y = sx[r * 32 + c + 1];             \
            G0.z = sx[r * 32 + c + 2]; G0.w = sx[r * 32 + c + 3];             \
        } else G0 = make_float4(0.f, 0.f, 0.f, 0.f);                          \
        chunk = tid + 256;                                                    \
        r = chunk >> 4; c4 = chunk & 15;                                      \
        k = (KQ) + c4 * 4;                                                    \
        if (k < 4096) {                                                       \
            int rowi = sidx[r * 16 + (k >> 8)];                               \
            G1 = *(const float4*)&cemb[(size_t)rowi * 256 + (k & 255)];       \
        } else if (k < 4128) {                                                \
            int c = k - 4096;                                                 \
            G1.x = sx[r * 32 + c];     G1.y = sx[r * 32 + c + 1];             \
            G1.z = sx[r * 32 + c + 2]; G1.w = sx[r * 32 + c + 3];             \
        } else G1 = make_float4(0.f, 0.f, 0.f, 0.f);                          \
    }

__global__ __launch_bounds__(256) void first_gemm_kernel(
    const u16* __restrict__ BT, const float* __restrict__ bias,
    float* __restrict__ outF,
    const int* __restrict__ cidx, const float* __restrict__ cemb,
    const float* __restrict__ xnum)
{
    __shared__ __align__(16) u16 Ab[2][FBM * LDK];    //  9216 B, padded
    __shared__ __align__(16) u16 Bb[2][256 * 64];     // 65536 B, swizzled no-pad
    __shared__ int   sidx[FBM * 16];
    __shared__ float sx[FBM * 32];

    const int tid = threadIdx.x;
    const int lane = tid & 63;
    const int wv = tid >> 6;
    const int quad = lane >> 4;
    const int l16 = lane & 15;
    const int m0 = blockIdx.x * FBM;

#pragma unroll
    for (int i = 0; i < 2; i++) sidx[tid + i * 256] = cidx[m0 * 16 + tid + i * 256];
    {
        float4 v = *(const float4*)&xnum[(size_t)m0 * 32 + tid * 4];
        sx[tid * 4 + 0] = v.x; sx[tid * 4 + 1] = v.y;
        sx[tid * 4 + 2] = v.z; sx[tid * 4 + 3] = v.w;
    }
    __syncthreads();

    f32x4 acc[2][4];
#pragma unroll
    for (int i = 0; i < 2; i++)
#pragma unroll
        for (int j = 0; j < 4; j++) acc[i][j] = (f32x4){0.f, 0.f, 0.f, 0.f};

#define WRITE_A(BUF, G0, G1)                                                  \
    {                                                                         \
        int r = tid >> 4, c4 = tid & 15;                                      \
        u16* dst = &Ab[BUF][r * LDK + c4 * 4];                                \
        dst[0] = f2bf(G0.x); dst[1] = f2bf(G0.y);                             \
        dst[2] = f2bf(G0.z); dst[3] = f2bf(G0.w);                             \
        int chunk = tid + 256;                                                \
        r = chunk >> 4; c4 = chunk & 15;                                      \
        dst = &Ab[BUF][r * LDK + c4 * 4];                                     \
        dst[0] = f2bf(G1.x); dst[1] = f2bf(G1.y);                             \
        dst[2] = f2bf(G1.z); dst[3] = f2bf(G1.w);                             \
    }

#define DMA_B(BUF, KQ)                                                        \
    _Pragma("unroll")                                                         \
    for (int it = 0; it < 8; it++) {                                          \
        int chunk = it * 256 + tid;                                           \
        int r = chunk >> 3;                                                   \
        int c8 = (chunk & 7) ^ (r & 7);                                       \
        const u16* src = &BT[(size_t)r * 4160 + (KQ) + c8 * 8];               \
        __builtin_amdgcn_global_load_lds(                                     \
            (const __attribute__((address_space(1))) void*)src,               \
            (__attribute__((address_space(3))) void*)&Bb[BUF][(it * 256 + wv * 64) * 8], \
            16, 0, 0);                                                        \
    }

    float4 ga0, ga1;
    GATHER(0, ga0, ga1);
    WRITE_A(0, ga0, ga1);
    DMA_B(0, 0);
    GATHER(64, ga0, ga1);
    __syncthreads();   // tile 0 staged

    for (int k0 = 0; k0 < 4160; k0 += 64) {
        const int cur = (k0 >> 6) & 1, nxt = cur ^ 1;
        if (k0 + 64 < 4160) {
            WRITE_A(nxt, ga0, ga1);
            DMA_B(nxt, k0 + 64);
            if (k0 + 128 < 4160) GATHER(k0 + 128, ga0, ga1);
        }
#pragma unroll
        for (int kk = 0; kk < 64; kk += 32) {
            bf16x8 af[2], bfr[4];
#pragma unroll
            for (int i = 0; i < 2; i++)
                af[i] = *(const bf16x8*)&Ab[cur][(i * 16 + l16) * LDK + kk + quad * 8];
#pragma unroll
            for (int j = 0; j < 4; j++) {
                int row = wv * 64 + j * 16 + l16;
                int c8L = quad + (kk >> 3);
                bfr[j] = *(const bf16x8*)&Bb[cur][row * 64 + ((c8L ^ (row & 7)) * 8)];
            }
#pragma unroll
            for (int i = 0; i < 2; i++)
#pragma unroll
                for (int j = 0; j < 4; j++)
                    acc[i][j] = mfma16(af[i], bfr[j], acc[i][j]);
        }
        __syncthreads();
    }

#pragma unroll
    for (int i = 0; i < 2; i++) {
#pragma unroll
        for (int j = 0; j < 4; j++) {
            int col = wv * 64 + j * 16 + l16;
            float bs = bias[col];
#pragma unroll
            for (int r = 0; r < 4; r++) {
                int row = m0 + i * 16 + quad * 4 + r;
                outF[(size_t)row * 256 + col] = acc[i][j][r] + bs;
            }
        }
    }
}

// ---------------- fused layer PAIR: LN->FC1->FC2 (+res) x2, h in regs between ----------------
// r4-proven phase structure (BM=32, grid 512, weights direct from L2); the
// inter-layer h HBM round-trip is eliminated (C-layout registers + shfl LN).
__global__ __launch_bounds__(256, 2) void layer_pair_kernel(
    float* __restrict__ h,
    const float* __restrict__ ln_g, const float* __restrict__ ln_b,
    const u16* __restrict__ W1T, const float* __restrict__ b1s,
    const u16* __restrict__ W2T, const float* __restrict__ b2s,
    int l0)
{
    __shared__ __align__(16) u16 hn[32 * 264];    // 16896 B
    __shared__ __align__(16) u16 hid[32 * 520];   // 33280 B (reused as f32 store buf)
    __shared__ float red[256];                    //  1024 B
    const int tid  = threadIdx.x;
    const int lane = tid & 63;
    const int wv   = tid >> 6;
    const int quad = lane >> 4;
    const int l16  = lane & 15;
    const int m0   = blockIdx.x * 32;

    const u16* W1a = W1T + (size_t)l0 * 131072;
    const u16* W2a = W2T + (size_t)l0 * 131072;
    const u16* W1b = W1a + 131072;
    const u16* W2b = W2a + 131072;

    // ---- early: preload residual h in C-layout (latency covered by A+B) ----
    f32x4 rh[2][4];
#pragma unroll
    for (int i = 0; i < 2; i++)
#pragma unroll
        for (int j = 0; j < 4; j++) {
            int col = wv * 64 + j * 16 + l16;
#pragma unroll
            for (int r = 0; r < 4; r++)
                rh[i][j][r] = h[(size_t)(m0 + i * 16 + quad * 4 + r) * 256 + col];
        }

    // ---- phase A: LN(l0) wave-per-row coalesced ----
    {
        const float* g0 = ln_g + l0 * 256;
        const float* b0 = ln_b + l0 * 256;
        float4 gv4 = *(const float4*)&g0[lane * 4];
        float4 bv4 = *(const float4*)&b0[lane * 4];
#pragma unroll
        for (int rr = 0; rr < 8; rr++) {
            int row = rr * 4 + wv;
            float4 x = *(const float4*)&h[(size_t)(m0 + row) * 256 + lane * 4];
            float s  = x.x + x.y + x.z + x.w;
            float s2 = x.x * x.x + x.y * x.y + x.z * x.z + x.w * x.w;
#pragma unroll
            for (int o = 32; o > 0; o >>= 1) { s += __shfl_xor(s, o); s2 += __shfl_xor(s2, o); }
            float mu = s * (1.f / 256.f);
            float rs = rsqrtf(s2 * (1.f / 256.f) - mu * mu + 1e-5f);
            ushort4 o4;
            o4.x = f2bf((x.x - mu) * rs * gv4.x + bv4.x);
            o4.y = f2bf((x.y - mu) * rs * gv4.y + bv4.y);
            o4.z = f2bf((x.z - mu) * rs * gv4.z + bv4.z);
            o4.w = f2bf((x.w - mu) * rs * gv4.w + bv4.w);
            *(ushort4*)&hn[row * 264 + lane * 4] = o4;
        }
    }
    __syncthreads();

    f32x4 h_acc[2][4];   // running residual stream (C-layout)

#pragma unroll 1
    for (int half = 0; half < 2; half++) {
        const u16* W1 = half ? W1b : W1a;
        const u16* W2 = half ? W2b : W2a;
        const float* b1 = b1s + (l0 + half) * 512;
        const float* b2 = b2s + (l0 + half) * 256;

        // ---- FC1: wave owns 128 of 512 cols ----
        float b1v[8];
#pragma unroll
        for (int j = 0; j < 8; j++) b1v[j] = b1[wv * 128 + j * 16 + l16];
        f32x4 acc1[2][8];
#pragma unroll
        for (int i = 0; i < 2; i++)
#pragma unroll
            for (int j = 0; j < 8; j++) acc1[i][j] = (f32x4){0.f, 0.f, 0.f, 0.f};
#pragma unroll
        for (int kk = 0; kk < 256; kk += 32) {
            bf16x8 af0 = *(const bf16x8*)&hn[l16 * 264 + kk + quad * 8];
            bf16x8 af1 = *(const bf16x8*)&hn[(16 + l16) * 264 + kk + quad * 8];
            bf16x8 bw[8];
#pragma unroll
            for (int j = 0; j < 8; j++)
                bw[j] = *(const bf16x8*)&W1[(size_t)(wv * 128 + j * 16 + l16) * 256 + kk + quad * 8];
#pragma unroll
            for (int j = 0; j < 8; j++) {
                acc1[0][j] = mfma16(af0, bw[j], acc1[0][j]);
                acc1[1][j] = mfma16(af1, bw[j], acc1[1][j]);
            }
        }
#pragma unroll
        for (int i = 0; i < 2; i++)
#pragma unroll
            for (int j = 0; j < 8; j++)
#pragma unroll
                for (int r = 0; r < 4; r++) {
                    float v = acc1[i][j][r] + b1v[j];
                    v = v > 0.f ? v : 0.f;
                    hid[(i * 16 + quad * 4 + r) * 520 + wv * 128 + j * 16 + l16] = f2bf(v);
                }
        __syncthreads();

        // ---- FC2: wave owns 64 of 256 cols; h_acc = resid + out + b2 ----
        float b2v[4];
#pragma unroll
        for (int j = 0; j < 4; j++) b2v[j] = b2[wv * 64 + j * 16 + l16];
        f32x4 acc2[2][4];
#pragma unroll
        for (int i = 0; i < 2; i++)
#pragma unroll
            for (int j = 0; j < 4; j++) acc2[i][j] = (f32x4){0.f, 0.f, 0.f, 0.f};
#pragma unroll
        for (int kk = 0; kk < 512; kk += 32) {
            bf16x8 af0 = *(const bf16x8*)&hid[l16 * 520 + kk + quad * 8];
            bf16x8 af1 = *(const bf16x8*)&hid[(16 + l16) * 520 + kk + quad * 8];
            bf16x8 bw[4];
#pragma unroll
            for (int j = 0; j < 4; j++)
                bw[j] = *(const bf16x8*)&W2[(size_t)(wv * 64 + j * 16 + l16) * 512 + kk + quad * 8];
#pragma unroll
            for (int j = 0; j < 4; j++) {
                acc2[0][j] = mfma16(af0, bw[j], acc2[0][j]);
                acc2[1][j] = mfma16(af1, bw[j], acc2[1][j]);
            }
        }
#pragma unroll
        for (int i = 0; i < 2; i++)
#pragma unroll
            for (int j = 0; j < 4; j++)
#pragma unroll
                for (int r = 0; r < 4; r++) {
                    float base = (half == 0) ? rh[i][j][r] : h_acc[i][j][r];
                    h_acc[i][j][r] = base + acc2[i][j][r] + b2v[j];
                }
        __syncthreads();   // hid reads done (and red free)

        if (half == 0) {
            // ---- LN(l0+1) from registers: shfl stats + LDS cross-wave ----
#pragma unroll
            for (int i = 0; i < 2; i++)
#pragma unroll
                for (int r = 0; r < 4; r++) {
                    float a = h_acc[i][0][r] + h_acc[i][1][r] + h_acc[i][2][r] + h_acc[i][3][r];
                    float b = h_acc[i][0][r] * h_acc[i][0][r] + h_acc[i][1][r] * h_acc[i][1][r]
                            + h_acc[i][2][r] * h_acc[i][2][r] + h_acc[i][3][r] * h_acc[i][3][r];
#pragma unroll
                    for (int o = 1; o < 16; o <<= 1) { a += __shfl_xor(a, o); b += __shfl_xor(b, o); }
                    if (l16 == 0) {
                        int row = i * 16 + quad * 4 + r;
                        red[row * 4 + wv] = a;
                        red[128 + row * 4 + wv] = b;
                    }
                }
            __syncthreads();
            const float* g1 = ln_g + (l0 + 1) * 256;
            const float* bb1 = ln_b + (l0 + 1) * 256;
            float gv[4], bv[4];
#pragma unroll
            for (int j = 0; j < 4; j++) {
                int col = wv * 64 + j * 16 + l16;
                gv[j] = g1[col];
                bv[j] = bb1[col];
            }
#pragma unroll
            for (int i = 0; i < 2; i++)
#pragma unroll
                for (int r = 0; r < 4; r++) {
                    int row = i * 16 + quad * 4 + r;
                    float4 sv = *(const float4*)&red[row * 4];
                    float4 qv = *(const float4*)&red[128 + row * 4];
                    float st = sv.x + sv.y + sv.z + sv.w;
                    float qt = qv.x + qv.y + qv.z + qv.w;
                    float m = st * (1.f / 256.f);
                    float rsv = rsqrtf(qt * (1.f / 256.f) - m * m + 1e-5f);
#pragma unroll
                    for (int j = 0; j < 4; j++) {
                        float v = (h_acc[i][j][r] - m) * rsv * gv[j] + bv[j];
                        hn[row * 264 + wv * 64 + j * 16 + l16] = f2bf(v);
                    }
                }
            __syncthreads();
        }
    }

    // ---- coalesced writeback via LDS (reuse hid as f32, stride 260) ----
    float* hstore = (float*)hid;
#pragma unroll
    for (int i = 0; i < 2; i++)
#pragma unroll
        for (int j = 0; j < 4; j++) {
            int col = wv * 64 + j * 16 + l16;
#pragma unroll
            for (int r = 0; r < 4; r++)
                hstore[(i * 16 + quad * 4 + r) * 260 + col] = h_acc[i][j][r];
        }
    __syncthreads();
#pragma unroll
    for (int rr = 0; rr < 8; rr++) {
        int row = rr * 4 + wv;
        float4 v = *(const float4*)&hstore[row * 260 + lane * 4];
        *(float4*)&h[(size_t)(m0 + row) * 256 + lane * 4] = v;
    }
}

// ---------------- head: final LN + [256 x 2] matvec ----------------
__global__ __launch_bounds__(256) void head_kernel(
    const float* __restrict__ h, const float* __restrict__ g,
    const float* __restrict__ bta, const float* __restrict__ Wh,
    const float* __restrict__ bh, float* __restrict__ out)
{
    int lane = threadIdx.x & 63;
    int row = blockIdx.x * 4 + (threadIdx.x >> 6);
    const float4 x = *(const float4*)&h[(size_t)row * 256 + lane * 4];
    float s = x.x + x.y + x.z + x.w;
    float s2 = x.x * x.x + x.y * x.y + x.z * x.z + x.w * x.w;
    for (int o = 32; o > 0; o >>= 1) { s += __shfl_xor(s, o); s2 += __shfl_xor(s2, o); }
    float mu = s * (1.f / 256.f);
    float rs = rsqrtf(s2 * (1.f / 256.f) - mu * mu + 1e-5f);
    float4 gv = *(const float4*)&g[lane * 4];
    float4 bv = *(const float4*)&bta[lane * 4];
    float xn0 = (x.x - mu) * rs * gv.x + bv.x;
    float xn1 = (x.y - mu) * rs * gv.y + bv.y;
    float xn2 = (x.z - mu) * rs * gv.z + bv.z;
    float xn3 = (x.w - mu) * rs * gv.w + bv.w;
    float4 wa = *(const float4*)&Wh[lane * 8];
    float4 wb = *(const float4*)&Wh[lane * 8 + 4];
    float d0 = xn0 * wa.x + xn1 * wa.z + xn2 * wb.x + xn3 * wb.z;
    float d1 = xn0 * wa.y + xn1 * wa.w + xn2 * wb.y + xn3 * wb.w;
    for (int o = 32; o > 0; o >>= 1) { d0 += __shfl_xor(d0, o); d1 += __shfl_xor(d1, o); }
    if (lane == 0) {
        out[(size_t)row * 2 + 0] = d0 + bh[0];
        out[(size_t)row * 2 + 1] = d1 + bh[1];
    }
}

// ---------------- launch ----------------
extern "C" void kernel_launch(void* const* d_in, const int* in_sizes, int n_in,
                              void* d_out, int out_size, void* d_ws, size_t ws_size,
                              hipStream_t stream)
{
    const float* x_num   = (const float*)d_in[0];
    const int*   cidx    = (const int*)d_in[1];
    const float* w_num   = (const float*)d_in[2];
    const float* b_num   = (const float*)d_in[3];
    const float* cemb    = (const float*)d_in[4];
    const float* W_first = (const float*)d_in[5];
    const float* b_first = (const float*)d_in[6];
    const float* ln_g    = (const float*)d_in[7];
    const float* ln_b    = (const float*)d_in[8];
    const float* W1s     = (const float*)d_in[9];
    const float* b1s     = (const float*)d_in[10];
    const float* W2s     = (const float*)d_in[11];
    const float* b2s     = (const float*)d_in[12];
    const float* g_f     = (const float*)d_in[13];
    const float* beta_f  = (const float*)d_in[14];
    const float* W_head  = (const float*)d_in[15];
    const float* b_head  = (const float*)d_in[16];
    float* out = (float*)d_out;

    char* ws = (char*)d_ws;
    float* U   = (float*)(ws + 0);          //  32 KB
    float* c0  = (float*)(ws + 32768);      //   1 KB
    float* P   = (float*)(ws + 33792);      //  32 KB
    u16* WcT   = (u16*)(ws + 66560);        // 256 x 4160 bf16
    u16* W1T   = (u16*)(ws + 2196480);      // 8 x 512 x 256 bf16
    u16* W2T   = (u16*)(ws + 4293632);      // 8 x 256 x 512 bf16
    float* h   = (float*)(ws + 6390784);    // 16384 x 256 f32

    prep_u_kernel<<<32, 256, 0, stream>>>(w_num, b_num, W_first, U, P);
    prep_c0_kernel<<<1, 256, 0, stream>>>(b_first, P, c0);
    transpose_kernel<<<dim3(64, 4, 1), 256, 0, stream>>>(
        W_first + (size_t)8192 * 256, WcT, 4096, 256, 4160, 0, 0, 0);
    transpose_kernel<<<dim3(1, 4, 1), 256, 0, stream>>>(
        U, WcT, 32, 256, 4160, 4096, 0, 0);
    transpose_kernel<<<dim3(4, 8, 8), 256, 0, stream>>>(
        W1s, W1T, 256, 512, 256, 0, 131072, 131072);
    transpose_kernel<<<dim3(8, 4, 8), 256, 0, stream>>>(
        W2s, W2T, 512, 256, 512, 0, 131072, 131072);

    first_gemm_kernel<<<512, 256, 0, stream>>>(
        WcT, c0, h, cidx, cemb, x_num);

    for (int lp = 0; lp < 4; lp++) {
        layer_pair_kernel<<<512, 256, 0, stream>>>(
            h, ln_g, ln_b, W1T, b1s, W2T, b2s, 2 * lp);
    }
    head_kernel<<<4096, 256, 0, stream>>>(h, g_f, beta_f, W_head, b_head, out);
}

// Round 8
// 507.796 us; speedup vs baseline: 1.6013x; 1.4160x over previous
//
#include <hip/hip_runtime.h>

typedef unsigned short u16;
typedef unsigned int u32;
typedef __attribute__((ext_vector_type(8))) short bf16x8;
typedef __attribute__((ext_vector_type(4))) float f32x4;

#define LDK 72   // A-tile LDS stride (64 + 8 pad)

__device__ __forceinline__ u16 f2bf(float f) {
    u32 u = __float_as_uint(f);
    u += 0x7fffu + ((u >> 16) & 1u);   // round-to-nearest-even
    return (u16)(u >> 16);
}

__device__ __forceinline__ f32x4 mfma16(bf16x8 a, bf16x8 b, f32x4 c) {
    return __builtin_amdgcn_mfma_f32_16x16x32_bf16(a, b, c, 0, 0, 0);
}

// ---------------- prep: fold numeric features ----------------

__global__ __launch_bounds__(256) void prep_u_kernel(
    const float* __restrict__ w_num, const float* __restrict__ b_num,
    const float* __restrict__ W_first, float* __restrict__ U, float* __restrict__ P)
{
    __shared__ float wrow[256];
    __shared__ float brow[256];
    int j = threadIdx.x, f = blockIdx.x;
    wrow[j] = w_num[f * 256 + j];
    brow[j] = b_num[f * 256 + j];
    __syncthreads();
    float au = 0.f, ap = 0.f;
    for (int k = 0; k < 256; k++) {
        float w = W_first[(size_t)((f << 8) + k) * 256 + j];
        au = fmaf(wrow[k], w, au);
        ap = fmaf(brow[k], w, ap);
    }
    U[f * 256 + j] = au;
    P[f * 256 + j] = ap;
}

__global__ __launch_bounds__(256) void prep_c0_kernel(
    const float* __restrict__ b_first, const float* __restrict__ P, float* __restrict__ c0)
{
    int j = threadIdx.x;
    float a = b_first[j];
    for (int f = 0; f < 32; f++) a += P[f * 256 + j];
    c0[j] = a;
}

// ---------------- prep: LDS-tiled transpose f32 -> bf16 ----------------
__global__ __launch_bounds__(256) void transpose_kernel(
    const float* __restrict__ in, u16* __restrict__ out,
    int R, int C, int ldo, int k_off, size_t in_stride, size_t out_stride)
{
    __shared__ float t[64][65];
    in  += (size_t)blockIdx.z * in_stride;
    out += (size_t)blockIdx.z * out_stride;
    const int tid = threadIdx.x;
    const int r0 = blockIdx.x * 64, c0 = blockIdx.y * 64;
#pragma unroll
    for (int i = 0; i < 16; i++) {
        int e = tid + i * 256;
        int r = e >> 6, c = e & 63;
        float v = (r0 + r < R) ? in[(size_t)(r0 + r) * C + c0 + c] : 0.f;
        t[c][r] = v;
    }
    __syncthreads();
#pragma unroll
    for (int i = 0; i < 2; i++) {
        int e = tid + i * 256;
        int c = e >> 3, r8 = (e & 7) * 8;
        u16 tmp[8];
#pragma unroll
        for (int x = 0; x < 8; x++) tmp[x] = f2bf(t[c][r8 + x]);
        *(bf16x8*)&out[(size_t)(c0 + c) * ldo + k_off + r0 + r8] = *(bf16x8*)tmp;
    }
}

// ---------------- first layer: gathered-A GEMM, ping-pong buffers ----------------
#define FBM 32

#define GATHER(KQ, G0, G1)                                                    \
    {                                                                         \
        int chunk = tid;                                                      \
        int r = chunk >> 4, c4 = chunk & 15;                                  \
        int k = (KQ) + c4 * 4;                                                \
        if (k < 4096) {                                                       \
            int rowi = sidx[r * 16 + (k >> 8)];                               \
            G0 = *(const float4*)&cemb[(size_t)rowi * 256 + (k & 255)];       \
        } else if (k < 4128) {                                                \
            int c = k - 4096;                                                 \
            G0.x = sx[r * 32 + c];     G0.y = sx[r * 32 + c + 1];             \
            G0.z = sx[r * 32 + c + 2]; G0.w = sx[r * 32 + c + 3];             \
        } else G0 = make_float4(0.f, 0.f, 0.f, 0.f);                          \
        chunk = tid + 256;                                                    \
        r = chunk >> 4; c4 = chunk & 15;                                      \
        k = (KQ) + c4 * 4;                                                    \
        if (k < 4096) {                                                       \
            int rowi = sidx[r * 16 + (k >> 8)];                               \
            G1 = *(const float4*)&cemb[(size_t)rowi * 256 + (k & 255)];       \
        } else if (k < 4128) {                                                \
            int c = k - 4096;                                                 \
            G1.x = sx[r * 32 + c];     G1.y = sx[r * 32 + c + 1];             \
            G1.z = sx[r * 32 + c + 2]; G1.w = sx[r * 32 + c + 3];             \
        } else G1 = make_float4(0.f, 0.f, 0.f, 0.f);                          \
    }

__global__ __launch_bounds__(256) void first_gemm_kernel(
    const u16* __restrict__ BT, const float* __restrict__ bias,
    float* __restrict__ outF,
    const int* __restrict__ cidx, const float* __restrict__ cemb,
    const float* __restrict__ xnum)
{
    __shared__ __align__(16) u16 Ab[2][FBM * LDK];    //  9216 B, padded
    __shared__ __align__(16) u16 Bb[2][256 * 64];     // 65536 B, swizzled no-pad
    __shared__ int   sidx[FBM * 16];
    __shared__ float sx[FBM * 32];

    const int tid = threadIdx.x;
    const int lane = tid & 63;
    const int wv = tid >> 6;
    const int quad = lane >> 4;
    const int l16 = lane & 15;
    const int m0 = blockIdx.x * FBM;

#pragma unroll
    for (int i = 0; i < 2; i++) sidx[tid + i * 256] = cidx[m0 * 16 + tid + i * 256];
    {
        float4 v = *(const float4*)&xnum[(size_t)m0 * 32 + tid * 4];
        sx[tid * 4 + 0] = v.x; sx[tid * 4 + 1] = v.y;
        sx[tid * 4 + 2] = v.z; sx[tid * 4 + 3] = v.w;
    }
    __syncthreads();

    f32x4 acc[2][4];
#pragma unroll
    for (int i = 0; i < 2; i++)
#pragma unroll
        for (int j = 0; j < 4; j++) acc[i][j] = (f32x4){0.f, 0.f, 0.f, 0.f};

#define WRITE_A(BUF, G0, G1)                                                  \
    {                                                                         \
        int r = tid >> 4, c4 = tid & 15;                                      \
        u16* dst = &Ab[BUF][r * LDK + c4 * 4];                                \
        dst[0] = f2bf(G0.x); dst[1] = f2bf(G0.y);                             \
        dst[2] = f2bf(G0.z); dst[3] = f2bf(G0.w);                             \
        int chunk = tid + 256;                                                \
        r = chunk >> 4; c4 = chunk & 15;                                      \
        dst = &Ab[BUF][r * LDK + c4 * 4];                                     \
        dst[0] = f2bf(G1.x); dst[1] = f2bf(G1.y);                             \
        dst[2] = f2bf(G1.z); dst[3] = f2bf(G1.w);                             \
    }

#define DMA_B(BUF, KQ)                                                        \
    _Pragma("unroll")                                                         \
    for (int it = 0; it < 8; it++) {                                          \
        int chunk = it * 256 + tid;                                           \
        int r = chunk >> 3;                                                   \
        int c8 = (chunk & 7) ^ (r & 7);                                       \
        const u16* src = &BT[(size_t)r * 4160 + (KQ) + c8 * 8];               \
        __builtin_amdgcn_global_load_lds(                                     \
            (const __attribute__((address_space(1))) void*)src,               \
            (__attribute__((address_space(3))) void*)&Bb[BUF][(it * 256 + wv * 64) * 8], \
            16, 0, 0);                                                        \
    }

    float4 ga0, ga1;
    GATHER(0, ga0, ga1);
    WRITE_A(0, ga0, ga1);
    DMA_B(0, 0);
    GATHER(64, ga0, ga1);
    __syncthreads();   // tile 0 staged

    for (int k0 = 0; k0 < 4160; k0 += 64) {
        const int cur = (k0 >> 6) & 1, nxt = cur ^ 1;
        if (k0 + 64 < 4160) {
            WRITE_A(nxt, ga0, ga1);
            DMA_B(nxt, k0 + 64);
            if (k0 + 128 < 4160) GATHER(k0 + 128, ga0, ga1);
        }
#pragma unroll
        for (int kk = 0; kk < 64; kk += 32) {
            bf16x8 af[2], bfr[4];
#pragma unroll
            for (int i = 0; i < 2; i++)
                af[i] = *(const bf16x8*)&Ab[cur][(i * 16 + l16) * LDK + kk + quad * 8];
#pragma unroll
            for (int j = 0; j < 4; j++) {
                int row = wv * 64 + j * 16 + l16;
                int c8L = quad + (kk >> 3);
                bfr[j] = *(const bf16x8*)&Bb[cur][row * 64 + ((c8L ^ (row & 7)) * 8)];
            }
#pragma unroll
            for (int i = 0; i < 2; i++)
#pragma unroll
                for (int j = 0; j < 4; j++)
                    acc[i][j] = mfma16(af[i], bfr[j], acc[i][j]);
        }
        __syncthreads();
    }

#pragma unroll
    for (int i = 0; i < 2; i++) {
#pragma unroll
        for (int j = 0; j < 4; j++) {
            int col = wv * 64 + j * 16 + l16;
            float bs = bias[col];
#pragma unroll
            for (int r = 0; r < 4; r++) {
                int row = m0 + i * 16 + quad * 4 + r;
                outF[(size_t)row * 256 + col] = acc[i][j][r] + bs;
            }
        }
    }
}

// ---------------- fused residual layer: BM=64, 512 threads, 1 block/CU ----------------
// 8 waves; each wave owns 64 FC1 cols / 32 FC2 cols but ALL 4 row-groups:
// 16 MFMAs per 4 weight loads (4:1) vs 2:1 in prior rounds. grid 256 = 1 block/CU;
// per-layer weight L2 traffic halves (128 MB). hid LDS reused as fp32 staging
// for a coalesced writeback that re-reads the residual row-major.
__global__ __launch_bounds__(512, 2) void layer_kernel(
    float* __restrict__ h,
    const float* __restrict__ g, const float* __restrict__ bta,
    const u16* __restrict__ W1, const float* __restrict__ b1,
    const u16* __restrict__ W2, const float* __restrict__ b2)
{
    __shared__ __align__(16) u16 hn[64 * 264];    // 33792 B
    __shared__ __align__(16) u16 hid[64 * 520];   // 66560 B (== f32 64 x 260)
    const int tid  = threadIdx.x;
    const int lane = tid & 63;
    const int wv   = tid >> 6;        // 0..7
    const int quad = lane >> 4;
    const int l16  = lane & 15;
    const int m0   = blockIdx.x * 64;

    // ---- phase A: LN (wave per row, 8 rounds, coalesced) ----
    float4 gv4 = *(const float4*)&g[lane * 4];
    float4 bv4 = *(const float4*)&bta[lane * 4];
#pragma unroll
    for (int rr = 0; rr < 8; rr++) {
        int row = rr * 8 + wv;
        float4 x = *(const float4*)&h[(size_t)(m0 + row) * 256 + lane * 4];
        float s  = x.x + x.y + x.z + x.w;
        float s2 = x.x * x.x + x.y * x.y + x.z * x.z + x.w * x.w;
#pragma unroll
        for (int o = 32; o > 0; o >>= 1) { s += __shfl_xor(s, o); s2 += __shfl_xor(s2, o); }
        float mu = s * (1.f / 256.f);
        float rs = rsqrtf(s2 * (1.f / 256.f) - mu * mu + 1e-5f);
        ushort4 o4;
        o4.x = f2bf((x.x - mu) * rs * gv4.x + bv4.x);
        o4.y = f2bf((x.y - mu) * rs * gv4.y + bv4.y);
        o4.z = f2bf((x.z - mu) * rs * gv4.z + bv4.z);
        o4.w = f2bf((x.w - mu) * rs * gv4.w + bv4.w);
        *(ushort4*)&hn[row * 264 + lane * 4] = o4;
    }
    __syncthreads();

    // ---- phase B: FC1, wave owns cols [wv*64, wv*64+64), all 64 rows ----
    float b1v[4];
#pragma unroll
    for (int j = 0; j < 4; j++) b1v[j] = b1[wv * 64 + j * 16 + l16];
    f32x4 acc1[4][4];
#pragma unroll
    for (int i = 0; i < 4; i++)
#pragma unroll
        for (int j = 0; j < 4; j++) acc1[i][j] = (f32x4){0.f, 0.f, 0.f, 0.f};
#pragma unroll
    for (int kk = 0; kk < 256; kk += 32) {
        bf16x8 af[4], bw[4];
#pragma unroll
        for (int i = 0; i < 4; i++)
            af[i] = *(const bf16x8*)&hn[(i * 16 + l16) * 264 + kk + quad * 8];
#pragma unroll
        for (int j = 0; j < 4; j++)
            bw[j] = *(const bf16x8*)&W1[(size_t)(wv * 64 + j * 16 + l16) * 256 + kk + quad * 8];
#pragma unroll
        for (int i = 0; i < 4; i++)
#pragma unroll
            for (int j = 0; j < 4; j++)
                acc1[i][j] = mfma16(af[i], bw[j], acc1[i][j]);
    }
#pragma unroll
    for (int i = 0; i < 4; i++)
#pragma unroll
        for (int j = 0; j < 4; j++)
#pragma unroll
            for (int r = 0; r < 4; r++) {
                float v = acc1[i][j][r] + b1v[j];
                v = v > 0.f ? v : 0.f;
                hid[(i * 16 + quad * 4 + r) * 520 + wv * 64 + j * 16 + l16] = f2bf(v);
            }
    __syncthreads();

    // ---- phase C: FC2, wave owns cols [wv*32, wv*32+32), all 64 rows ----
    float b2v[2];
#pragma unroll
    for (int j = 0; j < 2; j++) b2v[j] = b2[wv * 32 + j * 16 + l16];
    f32x4 acc2[4][2];
#pragma unroll
    for (int i = 0; i < 4; i++)
#pragma unroll
        for (int j = 0; j < 2; j++) acc2[i][j] = (f32x4){0.f, 0.f, 0.f, 0.f};
#pragma unroll
    for (int kk = 0; kk < 512; kk += 32) {
        bf16x8 af[4], bw[2];
#pragma unroll
        for (int i = 0; i < 4; i++)
            af[i] = *(const bf16x8*)&hid[(i * 16 + l16) * 520 + kk + quad * 8];
#pragma unroll
        for (int j = 0; j < 2; j++)
            bw[j] = *(const bf16x8*)&W2[(size_t)(wv * 32 + j * 16 + l16) * 512 + kk + quad * 8];
#pragma unroll
        for (int i = 0; i < 4; i++)
#pragma unroll
            for (int j = 0; j < 2; j++)
                acc2[i][j] = mfma16(af[i], bw[j], acc2[i][j]);
    }
    __syncthreads();   // all hid reads done before reuse as hstore

    // ---- stage FC2 output (+bias) to LDS fp32, then coalesced +resid writeback ----
    float* hstore = (float*)hid;   // 64 x 260
#pragma unroll
    for (int i = 0; i < 4; i++)
#pragma unroll
        for (int j = 0; j < 2; j++) {
            int col = wv * 32 + j * 16 + l16;
#pragma unroll
            for (int r = 0; r < 4; r++)
                hstore[(i * 16 + quad * 4 + r) * 260 + col] = acc2[i][j][r] + b2v[j];
        }
    __syncthreads();
#pragma unroll
    for (int rr = 0; rr < 8; rr++) {
        int row = rr * 8 + wv;
        float4 v = *(const float4*)&hstore[row * 260 + lane * 4];
        float4 res = *(const float4*)&h[(size_t)(m0 + row) * 256 + lane * 4];
        v.x += res.x; v.y += res.y; v.z += res.z; v.w += res.w;
        *(float4*)&h[(size_t)(m0 + row) * 256 + lane * 4] = v;
    }
}

// ---------------- head: final LN + [256 x 2] matvec ----------------
__global__ __launch_bounds__(256) void head_kernel(
    const float* __restrict__ h, const float* __restrict__ g,
    const float* __restrict__ bta, const float* __restrict__ Wh,
    const float* __restrict__ bh, float* __restrict__ out)
{
    int lane = threadIdx.x & 63;
    int row = blockIdx.x * 4 + (threadIdx.x >> 6);
    const float4 x = *(const float4*)&h[(size_t)row * 256 + lane * 4];
    float s = x.x + x.y + x.z + x.w;
    float s2 = x.x * x.x + x.y * x.y + x.z * x.z + x.w * x.w;
    for (int o = 32; o > 0; o >>= 1) { s += __shfl_xor(s, o); s2 += __shfl_xor(s2, o); }
    float mu = s * (1.f / 256.f);
    float rs = rsqrtf(s2 * (1.f / 256.f) - mu * mu + 1e-5f);
    float4 gv = *(const float4*)&g[lane * 4];
    float4 bv = *(const float4*)&bta[lane * 4];
    float xn0 = (x.x - mu) * rs * gv.x + bv.x;
    float xn1 = (x.y - mu) * rs * gv.y + bv.y;
    float xn2 = (x.z - mu) * rs * gv.z + bv.z;
    float xn3 = (x.w - mu) * rs * gv.w + bv.w;
    float4 wa = *(const float4*)&Wh[lane * 8];
    float4 wb = *(const float4*)&Wh[lane * 8 + 4];
    float d0 = xn0 * wa.x + xn1 * wa.z + xn2 * wb.x + xn3 * wb.z;
    float d1 = xn0 * wa.y + xn1 * wa.w + xn2 * wb.y + xn3 * wb.w;
    for (int o = 32; o > 0; o >>= 1) { d0 += __shfl_xor(d0, o); d1 += __shfl_xor(d1, o); }
    if (lane == 0) {
        out[(size_t)row * 2 + 0] = d0 + bh[0];
        out[(size_t)row * 2 + 1] = d1 + bh[1];
    }
}

// ---------------- launch ----------------
extern "C" void kernel_launch(void* const* d_in, const int* in_sizes, int n_in,
                              void* d_out, int out_size, void* d_ws, size_t ws_size,
                              hipStream_t stream)
{
    const float* x_num   = (const float*)d_in[0];
    const int*   cidx    = (const int*)d_in[1];
    const float* w_num   = (const float*)d_in[2];
    const float* b_num   = (const float*)d_in[3];
    const float* cemb    = (const float*)d_in[4];
    const float* W_first = (const float*)d_in[5];
    const float* b_first = (const float*)d_in[6];
    const float* ln_g    = (const float*)d_in[7];
    const float* ln_b    = (const float*)d_in[8];
    const float* W1s     = (const float*)d_in[9];
    const float* b1s     = (const float*)d_in[10];
    const float* W2s     = (const float*)d_in[11];
    const float* b2s     = (const float*)d_in[12];
    const float* g_f     = (const float*)d_in[13];
    const float* beta_f  = (const float*)d_in[14];
    const float* W_head  = (const float*)d_in[15];
    const float* b_head  = (const float*)d_in[16];
    float* out = (float*)d_out;

    char* ws = (char*)d_ws;
    float* U   = (float*)(ws + 0);          //  32 KB
    float* c0  = (float*)(ws + 32768);      //   1 KB
    float* P   = (float*)(ws + 33792);      //  32 KB
    u16* WcT   = (u16*)(ws + 66560);        // 256 x 4160 bf16
    u16* W1T   = (u16*)(ws + 2196480);      // 8 x 512 x 256 bf16
    u16* W2T   = (u16*)(ws + 4293632);      // 8 x 256 x 512 bf16
    float* h   = (float*)(ws + 6390784);    // 16384 x 256 f32

    prep_u_kernel<<<32, 256, 0, stream>>>(w_num, b_num, W_first, U, P);
    prep_c0_kernel<<<1, 256, 0, stream>>>(b_first, P, c0);
    transpose_kernel<<<dim3(64, 4, 1), 256, 0, stream>>>(
        W_first + (size_t)8192 * 256, WcT, 4096, 256, 4160, 0, 0, 0);
    transpose_kernel<<<dim3(1, 4, 1), 256, 0, stream>>>(
        U, WcT, 32, 256, 4160, 4096, 0, 0);
    transpose_kernel<<<dim3(4, 8, 8), 256, 0, stream>>>(
        W1s, W1T, 256, 512, 256, 0, 131072, 131072);
    transpose_kernel<<<dim3(8, 4, 8), 256, 0, stream>>>(
        W2s, W2T, 512, 256, 512, 0, 131072, 131072);

    first_gemm_kernel<<<512, 256, 0, stream>>>(
        WcT, c0, h, cidx, cemb, x_num);

    for (int l = 0; l < 8; l++) {
        layer_kernel<<<256, 512, 0, stream>>>(
            h, ln_g + l * 256, ln_b + l * 256,
            W1T + (size_t)l * 131072, b1s + l * 512,
            W2T + (size_t)l * 131072, b2s + l * 256);
    }
    head_kernel<<<4096, 256, 0, stream>>>(h, g_f, beta_f, W_head, b_head, out);
}